// Round 4
// baseline (208.413 us; speedup 1.0000x reference)
//
#include <hip/hip_runtime.h>
#include <hip/hip_bf16.h>

// Problem dims (fixed by reference setup_inputs)
static constexpr int BATCH = 4096;  // M
static constexpr int DIN   = 2048;  // K of GEMM1
static constexpr int HDIM  = 2048;  // N1 = K2 = N2
static constexpr int ADIM  = 5;

typedef __attribute__((ext_vector_type(8))) short short8;
typedef __attribute__((ext_vector_type(4))) float floatx4;

// ---- bf16 helpers (RNE) ----
__device__ __forceinline__ unsigned short f2bf(float f) {
  unsigned int u = __float_as_uint(f);
  unsigned int r = (u + 0x7fffu + ((u >> 16) & 1u)) >> 16;
  return (unsigned short)r;
}
__device__ __forceinline__ float bf2f(unsigned short u) {
  return __uint_as_float(((unsigned int)u) << 16);
}

// ---- 1) fused prep: x->bf16 (8192 blocks) + 2 transposes (1024 each) ----
// Transpose in 64x64 tiles: 128 B contiguous write segments (vs 64 B in R3).
__global__ __launch_bounds__(256) void k_prep(const float* __restrict__ x,
                                              const float* __restrict__ W_in,
                                              const float* __restrict__ W_snn,
                                              unsigned short* __restrict__ xb,
                                              unsigned short* __restrict__ WinT,
                                              unsigned short* __restrict__ WsnT) {
  __shared__ float tl[64][65];  // 16.6 KB; [c][r] read stride 65 -> conflict-free
  const int b = blockIdx.x;
  if (b < 8192) {
    const int i = b * 256 + threadIdx.x;
    float4 v = ((const float4*)x)[i];
    ushort4 o;
    o.x = f2bf(v.x); o.y = f2bf(v.y); o.z = f2bf(v.z); o.w = f2bf(v.w);
    ((ushort4*)xb)[i] = o;
  } else {
    int bi = b - 8192;  // 0..2047
    const float* src;
    unsigned short* dst;
    if (bi < 1024) { src = W_in; dst = WinT; }
    else           { src = W_snn; dst = WsnT; bi -= 1024; }
    const int bx = bi & 31, by = bi >> 5;  // 32x32 grid of 64x64 tiles
    const int c0 = bx * 64, r0 = by * 64;
    const int tx = threadIdx.x & 63, ty = threadIdx.x >> 6;  // 64 x 4
    #pragma unroll
    for (int s = 0; s < 64; s += 4)
      tl[ty + s][tx] = src[(size_t)(r0 + ty + s) * 2048 + (c0 + tx)];
    __syncthreads();
    #pragma unroll
    for (int s = 0; s < 64; s += 4)
      dst[(size_t)(c0 + ty + s) * 2048 + (r0 + tx)] = f2bf(tl[tx][ty + s]);
  }
}

// ---- 2) bf16 MFMA GEMM: BM=256 BN=128 BK=64, 512 thr = 8 waves 2Mx2Nx2KK ----
// 3-buffer LDS (144 KB), depth-2 prefetch, counted s_waitcnt vmcnt(6) + raw
// s_barrier once per K-tile (never drain to 0 in steady state). Per-wave
// output 128x64 with kk-split (half the K-slots); pair-sum epilogue via LDS.
// LDS XOR-swizzle (16B slot ^= row&7) via pre-swizzled global source addrs;
// global_load_lds dest linear (0 bank conflicts measured R1-R3).
// A: [M][K] bf16 row-major; BT: [N][K] bf16; C = A*B + bias.
// MODE 0: store bf16(acc+bias).  MODE 1: 10-step LIF closed form -> count.
template <int MODE>
__global__ __launch_bounds__(512, 2) void k_gemm(const unsigned short* __restrict__ Ag,
                                                 const unsigned short* __restrict__ BTg,
                                                 const float* __restrict__ bias,
                                                 unsigned short* __restrict__ outb,
                                                 int M, int N, int K) {
  constexpr int BK = 64;
  // per buffer: A bytes [0,32768), B bytes [32768,49152)
  __shared__ unsigned short smem[3][24576];  // 147456 B

  const int nbn = N / 128;           // 16
  const int nwg = gridDim.x;         // 256, %8==0 -> bijective XCD swizzle
  const int wg  = blockIdx.x;
  const int cpx = nwg >> 3;
  const int swz = (wg & 7) * cpx + (wg >> 3);
  const int bm = swz / nbn, bn = swz % nbn;
  const int m0 = bm * 256, n0 = bn * 128;

  const int t = threadIdx.x;
  const int l = t & 63;
  const int w = t >> 6;          // 0..7
  const int wc   = w & 1;        // N-half
  const int wrow = (w >> 1) & 1; // M-half
  const int kkh  = w >> 2;       // K-slot half (kk-split)

  // staging: thread t, instr j -> LDS bytes [t*16 + j*8192, +16) (linear dest)
  // phys row = t/8 + j*64 ; phys slot = t&7 ; source K-group = slot ^ (row&7)
  // (j*64 == 0 mod 8 -> same xor for all j)
  const int srow = t >> 3;
  const int sg = (((t & 7) ^ (srow & 7)) << 3);  // bf16 elems
  const unsigned short* gA = Ag + (size_t)(m0 + srow) * K + sg;
  const unsigned short* gB = BTg + (size_t)(n0 + srow) * K + sg;

  const int NT = K / BK;  // 32

  auto stage = [&](int tt, int buf) {
    const int kt = tt * BK;
    char* base = (char*)&smem[buf][0];
    #pragma unroll
    for (int j = 0; j < 4; ++j)
      __builtin_amdgcn_global_load_lds(
          (const __attribute__((address_space(1))) void*)(gA + (size_t)j * 64 * K + kt),
          (__attribute__((address_space(3))) void*)(base + t * 16 + j * 8192), 16, 0, 0);
    #pragma unroll
    for (int j = 0; j < 2; ++j)
      __builtin_amdgcn_global_load_lds(
          (const __attribute__((address_space(1))) void*)(gB + (size_t)j * 64 * K + kt),
          (__attribute__((address_space(3))) void*)(base + 32768 + t * 16 + j * 8192), 16, 0, 0);
  };

  // fragment reads (swizzled): byte = row*128 + ((slot ^ (row&7))<<4)
  // wave's K-slots: slot = kkh*4 + (l>>4); its rows all have row&7 == l&7
  const int soff = (((kkh << 2) | (l >> 4)) ^ (l & 7)) << 4;
  const int rA0 = (wrow * 128 + (l & 15)) * 128 + soff;          // + i*2048
  const int rB0 = 32768 + (wc * 64 + (l & 15)) * 128 + soff;     // + j*2048

  floatx4 acc[8][4] = {};

  // prologue: tiles 0,1 in flight (12 loads/thread); wait tile0 (leave 6)
  stage(0, 0);
  stage(1, 1);
  asm volatile("s_waitcnt vmcnt(6)" ::: "memory");
  __builtin_amdgcn_s_barrier();

  int cur = 0;
  for (int tt = 0; tt < NT; ++tt) {
    const char* Ab = (const char*)&smem[cur][0];
    short8 bf[4];
    #pragma unroll
    for (int j = 0; j < 4; ++j)
      bf[j] = *(const short8*)(Ab + rB0 + j * 2048);
    // issue depth-2 prefetch while reads/MFMAs run
    if (tt + 2 < NT) {
      int b2 = cur + 2; if (b2 >= 3) b2 -= 3;
      stage(tt + 2, b2);
    }
    {
      short8 af[4];
      #pragma unroll
      for (int i = 0; i < 4; ++i)
        af[i] = *(const short8*)(Ab + rA0 + i * 2048);
      #pragma unroll
      for (int i = 0; i < 4; ++i)
        #pragma unroll
        for (int j = 0; j < 4; ++j)
          acc[i][j] = __builtin_amdgcn_mfma_f32_16x16x32_bf16(af[i], bf[j],
                                                              acc[i][j], 0, 0, 0);
    }
    {
      short8 af[4];
      #pragma unroll
      for (int i = 0; i < 4; ++i)
        af[i] = *(const short8*)(Ab + rA0 + (i + 4) * 2048);
      #pragma unroll
      for (int i = 0; i < 4; ++i)
        #pragma unroll
        for (int j = 0; j < 4; ++j)
          acc[i + 4][j] = __builtin_amdgcn_mfma_f32_16x16x32_bf16(af[i], bf[j],
                                                                  acc[i + 4][j], 0, 0, 0);
    }
    // tile boundary: ensure tile tt+1 landed; keep tt+2's 6 loads in flight
    if (tt + 1 < NT) {
      if (tt + 2 < NT) asm volatile("s_waitcnt vmcnt(6)" ::: "memory");
      else             asm volatile("s_waitcnt vmcnt(0)" ::: "memory");
      __builtin_amdgcn_s_barrier();
    }
    cur = (cur == 2) ? 0 : cur + 1;
  }

  // ---- kk pair-sum epilogue: waves 4..7 donate acc via LDS (128 KB) ----
  __syncthreads();  // all waves done with tile buffers
  floatx4* xch = (floatx4*)&smem[0][0];
  if (kkh == 1) {
    #pragma unroll
    for (int i = 0; i < 8; ++i)
      #pragma unroll
      for (int j = 0; j < 4; ++j)
        xch[(w & 3) * 2048 + (i * 4 + j) * 64 + l] = acc[i][j];
  }
  __syncthreads();
  if (kkh == 0) {
    const int crow = m0 + wrow * 128 + ((l >> 4) << 2);  // + i*16 + r
    const int ccol = n0 + wc * 64 + (l & 15);            // + j*16
    #pragma unroll
    for (int j = 0; j < 4; ++j) {
      const int col = ccol + j * 16;
      const float bv = bias[col];
      #pragma unroll
      for (int i = 0; i < 8; ++i) {
        floatx4 a = acc[i][j];
        floatx4 o = xch[w * 2048 + (i * 4 + j) * 64 + l];
        const int row = crow + i * 16;
        #pragma unroll
        for (int r = 0; r < 4; ++r) {
          float v = a[r] + o[r] + bv;
          if (MODE == 1) {
            // LIF (tau=2, v_th=1, hard reset, v0=0, T=10), constant input v:
            // v_k = v*(1-2^-k); period k1 = min k with v_k >= 1; count = floor(10/k1)
            v = (v >= 2.0f)                ? 10.f
              : (v >= 1.3333333333333333f) ? 5.f
              : (v >= 1.1428571428571428f) ? 3.f
              : (v >= 1.0322580645161290f) ? 2.f
              : (v >= 1.0009775171065494f) ? 1.f : 0.f;
          }
          outb[(size_t)(row + r) * N + col] = f2bf(v);
        }
      }
    }
  }
}

// ---- 3) head: pre = 0.1*(cnt @ W_out) + b_out ; out = (pre/2 - 1 >= 0) ----
// 256 blocks x 16 rows (4 rows/wave): W_out LDS-stage traffic 10 MB total.
__global__ __launch_bounds__(256) void k_head(const unsigned short* __restrict__ cntb,
                                              const float* __restrict__ Wout,
                                              const float* __restrict__ bout,
                                              float* __restrict__ out) {
  __shared__ float Wl[HDIM * ADIM];  // 40 KB
  const int t = threadIdx.x;
  for (int i = t; i < HDIM * ADIM; i += 256) Wl[i] = Wout[i];
  __syncthreads();
  const int w = t >> 6, l = t & 63;
  #pragma unroll
  for (int rr = 0; rr < 4; ++rr) {
    const int row = blockIdx.x * 16 + w * 4 + rr;
    const unsigned short* rp = cntb + (size_t)row * HDIM;
    float acc[ADIM] = {};
    #pragma unroll
    for (int it = 0; it < 4; ++it) {
      const int k0 = it * 512 + l * 8;
      short8 v = *(const short8*)(rp + k0);
      #pragma unroll
      for (int jj = 0; jj < 8; ++jj) {
        const float c = bf2f((unsigned short)v[jj]);
        const int k = k0 + jj;
        #pragma unroll
        for (int a = 0; a < ADIM; ++a) acc[a] += c * Wl[k * ADIM + a];
      }
    }
    #pragma unroll
    for (int a = 0; a < ADIM; ++a)
      #pragma unroll
      for (int off = 32; off >= 1; off >>= 1)
        acc[a] += __shfl_down(acc[a], off, 64);
    if (l == 0) {
      #pragma unroll
      for (int a = 0; a < ADIM; ++a) {
        const float pre = acc[a] * 0.1f + bout[a];
        const float vout = pre * 0.5f;  // single-step LIF from v=0: v = pre/tau
        out[(size_t)row * ADIM + a] = (vout - 1.0f >= 0.0f) ? 1.0f : 0.0f;
      }
    }
  }
}

extern "C" void kernel_launch(void* const* d_in, const int* in_sizes, int n_in,
                              void* d_out, int out_size, void* d_ws, size_t ws_size,
                              hipStream_t stream) {
  const float* x     = (const float*)d_in[0];
  const float* W_in  = (const float*)d_in[1];
  const float* b_in  = (const float*)d_in[2];
  const float* W_snn = (const float*)d_in[3];
  const float* b_snn = (const float*)d_in[4];
  const float* W_out = (const float*)d_in[5];
  const float* b_out = (const float*)d_in[6];
  float* out = (float*)d_out;

  // workspace layout (48 MB):
  // [0,16M)   xb   : bf16 x [4096][2048]   (reused later for spike counts)
  // [16M,24M) WinT : bf16 W_in^T [2048][2048]
  // [24M,32M) WsnT : bf16 W_snn^T [2048][2048]
  // [32M,48M) hb   : bf16 h [4096][2048]
  char* ws = (char*)d_ws;
  unsigned short* xb   = (unsigned short*)(ws);
  unsigned short* WinT = (unsigned short*)(ws + (size_t)16 * 1024 * 1024);
  unsigned short* WsnT = (unsigned short*)(ws + (size_t)24 * 1024 * 1024);
  unsigned short* hb   = (unsigned short*)(ws + (size_t)32 * 1024 * 1024);
  unsigned short* cntb = xb;  // x no longer needed after GEMM1

  // 1) fused prep: cvt x (8192 blocks) + transpose W_in/W_snn (2048 blocks)
  k_prep<<<10240, 256, 0, stream>>>(x, W_in, W_snn, xb, WinT, WsnT);

  // 2) h = x @ W_in + b_in  (bf16 out)
  const int gblk = (BATCH / 256) * (HDIM / 128);  // 16*16 = 256, %8==0
  k_gemm<0><<<gblk, 512, 0, stream>>>(xb, WinT, b_in, hb, BATCH, HDIM, DIN);

  // 3) cur = h @ W_snn + b_snn ; fused 10-step LIF -> spike counts
  k_gemm<1><<<gblk, 512, 0, stream>>>(hb, WsnT, b_snn, cntb, BATCH, HDIM, HDIM);

  // 4) output head + output LIF threshold
  k_head<<<BATCH / 16, 256, 0, stream>>>(cntb, W_out, b_out, out);
}

// Round 5
// 203.193 us; speedup vs baseline: 1.0257x; 1.0257x over previous
//
#include <hip/hip_runtime.h>
#include <hip/hip_bf16.h>

// Problem dims (fixed by reference setup_inputs)
static constexpr int BATCH = 4096;  // M
static constexpr int DIN   = 2048;
static constexpr int HDIM  = 2048;
static constexpr int ADIM  = 5;

typedef __attribute__((ext_vector_type(8))) short short8;
typedef __attribute__((ext_vector_type(4))) float floatx4;

// ---- bf16 helpers (RNE) ----
__device__ __forceinline__ unsigned short f2bf(float f) {
  unsigned int u = __float_as_uint(f);
  unsigned int r = (u + 0x7fffu + ((u >> 16) & 1u)) >> 16;
  return (unsigned short)r;
}
__device__ __forceinline__ float bf2f(unsigned short u) {
  return __uint_as_float(((unsigned int)u) << 16);
}

// ---- 1) fused prep: cvt x (8192) + cvt W_in (4096) + transpose W_snn (1024)
//         + zero bc (1 block) ----
__global__ __launch_bounds__(256) void k_prep(const float* __restrict__ x,
                                              const float* __restrict__ W_in,
                                              const float* __restrict__ W_snn,
                                              unsigned short* __restrict__ xb,
                                              unsigned short* __restrict__ Winb,
                                              unsigned short* __restrict__ WsnT,
                                              float* __restrict__ bc) {
  __shared__ float tl[64][65];
  const int b = blockIdx.x;
  if (b < 12288) {
    // plain cvt: x (b<8192) then W_in
    const float4* src = (b < 8192) ? (const float4*)x : (const float4*)W_in;
    ushort4* dst = (b < 8192) ? (ushort4*)xb : (ushort4*)Winb;
    const int i = ((b < 8192) ? b : (b - 8192)) * 256 + threadIdx.x;
    float4 v = src[i];
    ushort4 o;
    o.x = f2bf(v.x); o.y = f2bf(v.y); o.z = f2bf(v.z); o.w = f2bf(v.w);
    dst[i] = o;
  } else if (b < 13312) {
    int bi = b - 12288;  // 0..1023: 64x64 transpose tiles of W_snn
    const int bx = bi & 31, by = bi >> 5;
    const int c0 = bx * 64, r0 = by * 64;
    const int tx = threadIdx.x & 63, ty = threadIdx.x >> 6;  // 64 x 4
    #pragma unroll
    for (int s = 0; s < 64; s += 4)
      tl[ty + s][tx] = W_snn[(size_t)(r0 + ty + s) * 2048 + (c0 + tx)];
    __syncthreads();
    #pragma unroll
    for (int s = 0; s < 64; s += 4)
      WsnT[(size_t)(c0 + ty + s) * 2048 + (r0 + tx)] = f2bf(tl[tx][ty + s]);
  } else {
    // zero bc[2048]
    #pragma unroll
    for (int s = 0; s < 8; ++s) bc[threadIdx.x + s * 256] = 0.0f;
  }
}

// ---- 2) bc = b_in @ W_snn (fp32, atomic partial sums; bc pre-zeroed) ----
__global__ __launch_bounds__(256) void k_bc(const float* __restrict__ b_in,
                                            const float* __restrict__ W_snn,
                                            float* __restrict__ bc) {
  const int t = threadIdx.x;
  const int k0 = blockIdx.x * 32;
  float a[8] = {};
  for (int k = k0; k < k0 + 32; ++k) {
    const float bv = b_in[k];
    const float* row = W_snn + (size_t)k * 2048;
    #pragma unroll
    for (int s = 0; s < 8; ++s) a[s] += bv * row[t + s * 256];
  }
  #pragma unroll
  for (int s = 0; s < 8; ++s) atomicAdd(&bc[t + s * 256], a[s]);
}

// ---- 3) GEMM-C: WcT = WsnT @ W_in  (C[i][j] = sum_k WsnT[i][k]*Winb[j][k])
// BM=128, BN=64, BK=64; 4 waves = 2M x 1N x 2KK, wave 64x64, acc[4][4].
// Double-buffer LDS 2 x 24 KB; same XOR-swizzle staging as R3 (0 conflicts).
__global__ __launch_bounds__(256, 2) void k_gemm_wc(const unsigned short* __restrict__ Ag,
                                                    const unsigned short* __restrict__ BTg,
                                                    unsigned short* __restrict__ outb) {
  constexpr int K = 2048, N = 2048;
  // per buffer: A bytes [0,16384), B bytes [16384,24576)
  __shared__ unsigned short smem[2][12288];  // 48 KB

  const int nbn = N / 64;            // 32
  const int nwg = gridDim.x;         // 512
  const int wg  = blockIdx.x;
  const int cpx = nwg >> 3;
  const int swz = (wg & 7) * cpx + (wg >> 3);
  const int bm = swz / nbn, bn = swz % nbn;
  const int m0 = bm * 128, n0 = bn * 64;

  const int t = threadIdx.x;
  const int l = t & 63;
  const int w = t >> 6;        // 0..3
  const int wrow = w & 1;      // M-half
  const int kkh  = w >> 1;     // K-group half

  const int srow = t >> 3;
  const int sg = (((t & 7) ^ (srow & 7)) << 3);
  const unsigned short* gA = Ag + (size_t)(m0 + srow) * K + sg;
  const unsigned short* gB = BTg + (size_t)(n0 + srow) * K + sg;

  auto stage = [&](int tt) {
    const int kt = tt * 64;
    char* base = (char*)&smem[tt & 1][0];
    #pragma unroll
    for (int j = 0; j < 4; ++j)
      __builtin_amdgcn_global_load_lds(
          (const __attribute__((address_space(1))) void*)(gA + (size_t)j * 32 * K + kt),
          (__attribute__((address_space(3))) void*)(base + t * 16 + j * 4096), 16, 0, 0);
    #pragma unroll
    for (int j = 0; j < 2; ++j)
      __builtin_amdgcn_global_load_lds(
          (const __attribute__((address_space(1))) void*)(gB + (size_t)j * 32 * K + kt),
          (__attribute__((address_space(3))) void*)(base + 16384 + t * 16 + j * 4096), 16, 0, 0);
  };

  const int soff = (((kkh << 2) | (l >> 4)) ^ (l & 7)) << 4;
  const int rA0 = (wrow * 64 + (l & 15)) * 128 + soff;   // + i*2048
  const int rB0 = 16384 + (l & 15) * 128 + soff;         // + j*2048

  floatx4 acc[4][4] = {};

  stage(0);
  __syncthreads();

  for (int tt = 0; tt < 32; ++tt) {
    if (tt + 1 < 32) stage(tt + 1);
    const char* Ab = (const char*)&smem[tt & 1][0];
    short8 bf[4], af[4];
    #pragma unroll
    for (int j = 0; j < 4; ++j) bf[j] = *(const short8*)(Ab + rB0 + j * 2048);
    #pragma unroll
    for (int i = 0; i < 4; ++i) af[i] = *(const short8*)(Ab + rA0 + i * 2048);
    #pragma unroll
    for (int i = 0; i < 4; ++i)
      #pragma unroll
      for (int j = 0; j < 4; ++j)
        acc[i][j] = __builtin_amdgcn_mfma_f32_16x16x32_bf16(af[i], bf[j],
                                                            acc[i][j], 0, 0, 0);
    __syncthreads();
  }

  // kk pair-sum via LDS (32 KB spans both buffers, all tiles done)
  floatx4* xch = (floatx4*)&smem[0][0];
  if (kkh == 1) {
    #pragma unroll
    for (int i = 0; i < 4; ++i)
      #pragma unroll
      for (int j = 0; j < 4; ++j)
        xch[wrow * 1024 + (i * 4 + j) * 64 + l] = acc[i][j];
  }
  __syncthreads();
  if (kkh == 0) {
    const int crow = m0 + wrow * 64 + ((l >> 4) << 2);
    const int ccol = n0 + (l & 15);
    #pragma unroll
    for (int j = 0; j < 4; ++j) {
      const int col = ccol + j * 16;
      #pragma unroll
      for (int i = 0; i < 4; ++i) {
        floatx4 a = acc[i][j];
        floatx4 o = xch[wrow * 1024 + (i * 4 + j) * 64 + l];
        const int row = crow + i * 16;
        #pragma unroll
        for (int r = 0; r < 4; ++r)
          outb[(size_t)(row + r) * N + col] = f2bf(a[r] + o[r]);
      }
    }
  }
}

// ---- 4) GEMM-X: cnt = LIF10(x @ Wc + bc + 0)  [R3 structure verbatim] ----
// BM=BN=128, BK=64; 4 waves = 1M x 2N x 2KK, wave 128x64 kk-split.
__global__ __launch_bounds__(256, 2) void k_gemm_lif(const unsigned short* __restrict__ Ag,
                                                     const unsigned short* __restrict__ BTg,
                                                     const float* __restrict__ bc,
                                                     const float* __restrict__ b_snn,
                                                     unsigned short* __restrict__ outb,
                                                     int M, int N, int K) {
  __shared__ unsigned short smem[2][16384];  // 64 KB

  const int nbn = N / 128;
  const int nwg = gridDim.x;  // 512
  const int wg  = blockIdx.x;
  const int cpx = nwg >> 3;
  const int swz = (wg & 7) * cpx + (wg >> 3);
  const int bm = swz / nbn, bn = swz % nbn;
  const int m0 = bm * 128, n0 = bn * 128;

  const int t = threadIdx.x;
  const int l = t & 63;
  const int w = t >> 6;
  const int wc  = w & 1;
  const int kkh = w >> 1;

  const int srow = t >> 3;
  const int sg = (((t & 7) ^ (srow & 7)) << 3);
  const unsigned short* gA = Ag + (size_t)(m0 + srow) * K + sg;
  const unsigned short* gB = BTg + (size_t)(n0 + srow) * K + sg;

  const int NT = K / 64;

  auto stage = [&](int tt) {
    const int kt = tt * 64;
    char* base = (char*)&smem[tt & 1][0];
    #pragma unroll
    for (int j = 0; j < 4; ++j)
      __builtin_amdgcn_global_load_lds(
          (const __attribute__((address_space(1))) void*)(gA + (size_t)j * 32 * K + kt),
          (__attribute__((address_space(3))) void*)(base + t * 16 + j * 4096), 16, 0, 0);
    #pragma unroll
    for (int j = 0; j < 4; ++j)
      __builtin_amdgcn_global_load_lds(
          (const __attribute__((address_space(1))) void*)(gB + (size_t)j * 32 * K + kt),
          (__attribute__((address_space(3))) void*)(base + 16384 + t * 16 + j * 4096), 16, 0, 0);
  };

  const int soff = (((kkh << 2) | (l >> 4)) ^ (l & 7)) << 4;
  const int rA0 = (l & 15) * 128 + soff;
  const int rB0 = 32768 + (wc * 64 + (l & 15)) * 128 + soff;

  floatx4 acc[8][4] = {};

  stage(0);
  __syncthreads();

  for (int tt = 0; tt < NT; ++tt) {
    if (tt + 1 < NT) stage(tt + 1);
    const char* Ab = (const char*)&smem[tt & 1][0];
    short8 bf[4];
    #pragma unroll
    for (int j = 0; j < 4; ++j) bf[j] = *(const short8*)(Ab + rB0 + j * 2048);
    {
      short8 af[4];
      #pragma unroll
      for (int i = 0; i < 4; ++i) af[i] = *(const short8*)(Ab + rA0 + i * 2048);
      #pragma unroll
      for (int i = 0; i < 4; ++i)
        #pragma unroll
        for (int j = 0; j < 4; ++j)
          acc[i][j] = __builtin_amdgcn_mfma_f32_16x16x32_bf16(af[i], bf[j],
                                                              acc[i][j], 0, 0, 0);
    }
    {
      short8 af[4];
      #pragma unroll
      for (int i = 0; i < 4; ++i) af[i] = *(const short8*)(Ab + rA0 + (i + 4) * 2048);
      #pragma unroll
      for (int i = 0; i < 4; ++i)
        #pragma unroll
        for (int j = 0; j < 4; ++j)
          acc[i + 4][j] = __builtin_amdgcn_mfma_f32_16x16x32_bf16(af[i], bf[j],
                                                                  acc[i + 4][j], 0, 0, 0);
    }
    __syncthreads();
  }

  floatx4* xch = (floatx4*)&smem[0][0];
  if (kkh == 1) {
    #pragma unroll
    for (int i = 0; i < 8; ++i)
      #pragma unroll
      for (int j = 0; j < 4; ++j)
        xch[wc * 2048 + (i * 4 + j) * 64 + l] = acc[i][j];
  }
  __syncthreads();
  if (kkh == 0) {
    const int crow = m0 + ((l >> 4) << 2);
    const int ccol = n0 + wc * 64 + (l & 15);
    #pragma unroll
    for (int j = 0; j < 4; ++j) {
      const int col = ccol + j * 16;
      const float bv = bc[col] + b_snn[col];
      #pragma unroll
      for (int i = 0; i < 8; ++i) {
        floatx4 a = acc[i][j];
        floatx4 o = xch[wc * 2048 + (i * 4 + j) * 64 + l];
        const int row = crow + i * 16;
        #pragma unroll
        for (int r = 0; r < 4; ++r) {
          float v = a[r] + o[r] + bv;
          // LIF (tau=2, v_th=1, hard reset, v0=0, T=10), constant input v:
          // v_k = v*(1-2^-k); period k1 = min k with v_k >= 1; count=floor(10/k1)
          v = (v >= 2.0f)                ? 10.f
            : (v >= 1.3333333333333333f) ? 5.f
            : (v >= 1.1428571428571428f) ? 3.f
            : (v >= 1.0322580645161290f) ? 2.f
            : (v >= 1.0009775171065494f) ? 1.f : 0.f;
          outb[(size_t)(row + r) * N + col] = f2bf(v);
        }
      }
    }
  }
}

// ---- 5) head: pre = 0.1*(cnt @ W_out) + b_out ; out = (pre/2 - 1 >= 0) ----
__global__ __launch_bounds__(256) void k_head(const unsigned short* __restrict__ cntb,
                                              const float* __restrict__ Wout,
                                              const float* __restrict__ bout,
                                              float* __restrict__ out) {
  __shared__ float Wl[HDIM * ADIM];  // 40 KB
  const int t = threadIdx.x;
  for (int i = t; i < HDIM * ADIM; i += 256) Wl[i] = Wout[i];
  __syncthreads();
  const int w = t >> 6, l = t & 63;
  #pragma unroll
  for (int rr = 0; rr < 4; ++rr) {
    const int row = blockIdx.x * 16 + w * 4 + rr;
    const unsigned short* rp = cntb + (size_t)row * HDIM;
    float acc[ADIM] = {};
    #pragma unroll
    for (int it = 0; it < 4; ++it) {
      const int k0 = it * 512 + l * 8;
      short8 v = *(const short8*)(rp + k0);
      #pragma unroll
      for (int jj = 0; jj < 8; ++jj) {
        const float c = bf2f((unsigned short)v[jj]);
        const int k = k0 + jj;
        #pragma unroll
        for (int a = 0; a < ADIM; ++a) acc[a] += c * Wl[k * ADIM + a];
      }
    }
    #pragma unroll
    for (int a = 0; a < ADIM; ++a)
      #pragma unroll
      for (int off = 32; off >= 1; off >>= 1)
        acc[a] += __shfl_down(acc[a], off, 64);
    if (l == 0) {
      #pragma unroll
      for (int a = 0; a < ADIM; ++a) {
        const float pre = acc[a] * 0.1f + bout[a];
        const float vout = pre * 0.5f;
        out[(size_t)row * ADIM + a] = (vout - 1.0f >= 0.0f) ? 1.0f : 0.0f;
      }
    }
  }
}

extern "C" void kernel_launch(void* const* d_in, const int* in_sizes, int n_in,
                              void* d_out, int out_size, void* d_ws, size_t ws_size,
                              hipStream_t stream) {
  const float* x     = (const float*)d_in[0];
  const float* W_in  = (const float*)d_in[1];
  const float* b_in  = (const float*)d_in[2];
  const float* W_snn = (const float*)d_in[3];
  const float* b_snn = (const float*)d_in[4];
  const float* W_out = (const float*)d_in[5];
  const float* b_out = (const float*)d_in[6];
  float* out = (float*)d_out;

  // workspace (<= 48 MB):
  // [0,16M)   xb   : bf16 x [4096][2048]
  // [16,24M)  Winb : bf16 W_in [2048][2048]      (dead after GEMM-C)
  // [24,32M)  WsnT : bf16 W_snn^T [2048][2048]   (dead after GEMM-C)
  // [32,40M)  WcT  : bf16 (W_in@W_snn)^T [2048][2048]
  // [16,32M)  cnt  : bf16 spike counts [4096][2048] (reuses Winb/WsnT)
  // [47M)     bc   : fp32 [2048]
  char* ws = (char*)d_ws;
  unsigned short* xb   = (unsigned short*)(ws);
  unsigned short* Winb = (unsigned short*)(ws + (size_t)16 * 1024 * 1024);
  unsigned short* WsnT = (unsigned short*)(ws + (size_t)24 * 1024 * 1024);
  unsigned short* WcT  = (unsigned short*)(ws + (size_t)32 * 1024 * 1024);
  unsigned short* cntb = Winb;
  float* bc = (float*)(ws + (size_t)47 * 1024 * 1024);

  // 1) prep: cvt x, cvt W_in, transpose W_snn, zero bc
  k_prep<<<13313, 256, 0, stream>>>(x, W_in, W_snn, xb, Winb, WsnT, bc);

  // 2) bc = b_in @ W_snn
  k_bc<<<64, 256, 0, stream>>>(b_in, W_snn, bc);

  // 3) WcT = WsnT @ W_in^T^T  (C[i][j] = sum_k W_snn[k][i] W_in[j][k] = Wc^T)
  k_gemm_wc<<<512, 256, 0, stream>>>(WsnT, Winb, WcT);

  // 4) cnt = LIF10(x @ Wc + bc + b_snn)
  k_gemm_lif<<<512, 256, 0, stream>>>(xb, WcT, bc, b_snn, cntb,
                                      BATCH, HDIM, DIN);

  // 5) head
  k_head<<<BATCH / 16, 256, 0, stream>>>(cntb, W_out, b_out, out);
}

// Round 6
// 196.734 us; speedup vs baseline: 1.0594x; 1.0328x over previous
//
#include <hip/hip_runtime.h>
#include <hip/hip_bf16.h>

// Problem dims (fixed by reference setup_inputs)
static constexpr int BATCH = 4096;  // M
static constexpr int DIN   = 2048;
static constexpr int HDIM  = 2048;
static constexpr int ADIM  = 5;

typedef __attribute__((ext_vector_type(8))) short short8;
typedef __attribute__((ext_vector_type(4))) float floatx4;

// ---- bf16 helpers (RNE) ----
__device__ __forceinline__ unsigned short f2bf(float f) {
  unsigned int u = __float_as_uint(f);
  unsigned int r = (u + 0x7fffu + ((u >> 16) & 1u)) >> 16;
  return (unsigned short)r;
}
__device__ __forceinline__ float bf2f(unsigned short u) {
  return __uint_as_float(((unsigned int)u) << 16);
}

// ---- 1) fused prep: cvt x (8192) + cvt W_in (4096) + transpose W_snn (1024)
//         + zero bc (1 block; bc lives in d_out scratch) ----
__global__ __launch_bounds__(256) void k_prep(const float* __restrict__ x,
                                              const float* __restrict__ W_in,
                                              const float* __restrict__ W_snn,
                                              unsigned short* __restrict__ xb,
                                              unsigned short* __restrict__ Winb,
                                              unsigned short* __restrict__ WsnT,
                                              float* __restrict__ bc) {
  __shared__ float tl[64][65];
  const int b = blockIdx.x;
  if (b < 12288) {
    const float4* src = (b < 8192) ? (const float4*)x : (const float4*)W_in;
    ushort4* dst = (b < 8192) ? (ushort4*)xb : (ushort4*)Winb;
    const int i = ((b < 8192) ? b : (b - 8192)) * 256 + threadIdx.x;
    float4 v = src[i];
    ushort4 o;
    o.x = f2bf(v.x); o.y = f2bf(v.y); o.z = f2bf(v.z); o.w = f2bf(v.w);
    dst[i] = o;
  } else if (b < 13312) {
    int bi = b - 12288;  // 0..1023: 64x64 transpose tiles of W_snn
    const int bx = bi & 31, by = bi >> 5;
    const int c0 = bx * 64, r0 = by * 64;
    const int tx = threadIdx.x & 63, ty = threadIdx.x >> 6;  // 64 x 4
    #pragma unroll
    for (int s = 0; s < 64; s += 4)
      tl[ty + s][tx] = W_snn[(size_t)(r0 + ty + s) * 2048 + (c0 + tx)];
    __syncthreads();
    #pragma unroll
    for (int s = 0; s < 64; s += 4)
      WsnT[(size_t)(c0 + ty + s) * 2048 + (r0 + tx)] = f2bf(tl[tx][ty + s]);
  } else {
    #pragma unroll
    for (int s = 0; s < 8; ++s) bc[threadIdx.x + s * 256] = 0.0f;
  }
}

// ---- 2) bc = b_in @ W_snn (fp32, atomic partial sums; bc pre-zeroed) ----
__global__ __launch_bounds__(256) void k_bc(const float* __restrict__ b_in,
                                            const float* __restrict__ W_snn,
                                            float* __restrict__ bc) {
  const int t = threadIdx.x;
  const int k0 = blockIdx.x * 32;
  float a[8] = {};
  for (int k = k0; k < k0 + 32; ++k) {
    const float bv = b_in[k];
    const float* row = W_snn + (size_t)k * 2048;
    #pragma unroll
    for (int s = 0; s < 8; ++s) a[s] += bv * row[t + s * 256];
  }
  #pragma unroll
  for (int s = 0; s < 8; ++s) atomicAdd(&bc[t + s * 256], a[s]);
}

// ---- 3) bf16 MFMA GEMM: 128x128 tile, BK=64, 512 thr = 8 waves 2Mx2Nx2KK ----
// Per-wave 64x64 output over half the K-slots (kk-split); pair-sum epilogue
// via LDS. 2-buf LDS (2 x 32 KB), R3's rhythm: stage(tt+1) -> ds_read ->
// 16 MFMA/wave -> __syncthreads, 2 blocks/CU x 8 waves = 16 waves/CU.
// LDS XOR-swizzle (16B slot ^= row&7) via pre-swizzled global source addrs
// (0 bank conflicts measured R1-R5). A: [M][2048] bf16; BT: [N][2048] bf16.
// MODE 0: split-K partial (grid 512 = 2 K-halves x 256 tiles, M=N=2048),
//         store bf16(acc) to outb + kh*2048*2048, no bias.
// MODE 1: full K (grid 512 tiles, M=4096), bias=bc+b_snn, 10-step LIF closed
//         form -> bf16 spike count.
template <int MODE>
__global__ __launch_bounds__(512, 4) void k_gemm(const unsigned short* __restrict__ Ag,
                                                 const unsigned short* __restrict__ BTg,
                                                 const float* __restrict__ bias_a,
                                                 const float* __restrict__ bias_b,
                                                 unsigned short* __restrict__ outb) {
  constexpr int Kfull = 2048;
  constexpr int NT = (MODE == 0) ? 16 : 32;
  // per buffer: A bytes [0,16384), B bytes [16384,32768)
  __shared__ unsigned short smem[2][16384];  // 64 KB

  const int nwg = gridDim.x;  // 512, %8==0 -> bijective XCD swizzle
  const int wg  = blockIdx.x;
  const int cpx = nwg >> 3;
  const int swz = (wg & 7) * cpx + (wg >> 3);
  int kh, tile;
  if (MODE == 0) { kh = swz >> 8; tile = swz & 255; }
  else           { kh = 0;        tile = swz;       }
  const int bm = tile >> 4, bn = tile & 15;   // nbn = 2048/128 = 16
  const int m0 = bm * 128, n0 = bn * 128;
  const int koff = kh << 10;

  const int t = threadIdx.x;
  const int l = t & 63;
  const int w = t >> 6;           // 0..7
  const int wn  = w & 1;          // N-half
  const int wm  = (w >> 1) & 1;   // M-half
  const int kkh = w >> 2;         // K-slot half (kk-split)

  // staging: thread t, instr j -> LDS bytes [t*16 + j*8192, +16) (linear dest)
  // phys row = t/8 + j*64 ; phys slot = t&7 ; source K-group = slot ^ (row&7)
  const int srow = t >> 3;  // 0..63
  const int sg = (((t & 7) ^ (srow & 7)) << 3);  // bf16 elems
  const unsigned short* gA = Ag + (size_t)(m0 + srow) * Kfull + koff + sg;
  const unsigned short* gB = BTg + (size_t)(n0 + srow) * Kfull + koff + sg;

  auto stage = [&](int tt) {
    const int kt = tt * 64;
    char* base = (char*)&smem[tt & 1][0];
    #pragma unroll
    for (int j = 0; j < 2; ++j)
      __builtin_amdgcn_global_load_lds(
          (const __attribute__((address_space(1))) void*)(gA + (size_t)j * 64 * Kfull + kt),
          (__attribute__((address_space(3))) void*)(base + t * 16 + j * 8192), 16, 0, 0);
    #pragma unroll
    for (int j = 0; j < 2; ++j)
      __builtin_amdgcn_global_load_lds(
          (const __attribute__((address_space(1))) void*)(gB + (size_t)j * 64 * Kfull + kt),
          (__attribute__((address_space(3))) void*)(base + 16384 + t * 16 + j * 8192), 16, 0, 0);
  };

  // fragment reads (swizzled): byte = row*128 + ((slot ^ (row&7))<<4)
  // wave's K-slots: slot = kkh*4 + (l>>4); its rows all have row&7 == l&7
  const int soff = (((kkh << 2) | (l >> 4)) ^ (l & 7)) << 4;
  const int rA0 = (wm * 64 + (l & 15)) * 128 + soff;           // + i*2048
  const int rB0 = 16384 + (wn * 64 + (l & 15)) * 128 + soff;   // + j*2048

  floatx4 acc[4][4] = {};

  stage(0);
  __syncthreads();

  for (int tt = 0; tt < NT; ++tt) {
    if (tt + 1 < NT) stage(tt + 1);
    const char* Ab = (const char*)&smem[tt & 1][0];
    short8 bf[4], af[4];
    #pragma unroll
    for (int j = 0; j < 4; ++j) bf[j] = *(const short8*)(Ab + rB0 + j * 2048);
    #pragma unroll
    for (int i = 0; i < 4; ++i) af[i] = *(const short8*)(Ab + rA0 + i * 2048);
    #pragma unroll
    for (int i = 0; i < 4; ++i)
      #pragma unroll
      for (int j = 0; j < 4; ++j)
        acc[i][j] = __builtin_amdgcn_mfma_f32_16x16x32_bf16(af[i], bf[j],
                                                            acc[i][j], 0, 0, 0);
    __syncthreads();
  }

  // ---- kk pair-sum epilogue: waves 4..7 donate acc via LDS (64 KB) ----
  floatx4* xch = (floatx4*)&smem[0][0];  // 4096 floatx4 = 64 KB (both bufs dead)
  if (kkh == 1) {
    #pragma unroll
    for (int i = 0; i < 4; ++i)
      #pragma unroll
      for (int j = 0; j < 4; ++j)
        xch[(w & 3) * 1024 + (i * 4 + j) * 64 + l] = acc[i][j];
  }
  __syncthreads();
  if (kkh == 0) {
    unsigned short* outp = outb + (size_t)kh * 2048 * 2048;
    const int crow = m0 + wm * 64 + ((l >> 4) << 2);  // + i*16 + r
    const int ccol = n0 + wn * 64 + (l & 15);         // + j*16
    #pragma unroll
    for (int j = 0; j < 4; ++j) {
      const int col = ccol + j * 16;
      float bv = 0.0f;
      if (MODE == 1) bv = bias_a[col] + bias_b[col];
      #pragma unroll
      for (int i = 0; i < 4; ++i) {
        floatx4 a = acc[i][j];
        floatx4 o = xch[w * 1024 + (i * 4 + j) * 64 + l];
        const int row = crow + i * 16;
        #pragma unroll
        for (int r = 0; r < 4; ++r) {
          float v = a[r] + o[r] + bv;
          if (MODE == 1) {
            // LIF (tau=2, v_th=1, hard reset, v0=0, T=10), constant input v:
            // v_k = v*(1-2^-k); period k1 = min k with v_k >= 1; count=floor(10/k1)
            v = (v >= 2.0f)                ? 10.f
              : (v >= 1.3333333333333333f) ? 5.f
              : (v >= 1.1428571428571428f) ? 3.f
              : (v >= 1.0322580645161290f) ? 2.f
              : (v >= 1.0009775171065494f) ? 1.f : 0.f;
          }
          outp[(size_t)(row + r) * 2048 + col] = f2bf(v);
        }
      }
    }
  }
}

// ---- 4) WcT = bf16(Cp0 + Cp1), in-place safe over Cp0 (i -> i) ----
__global__ __launch_bounds__(256) void k_wcred(const ushort4* __restrict__ a,
                                               const ushort4* __restrict__ b,
                                               ushort4* __restrict__ o) {
  const int i = blockIdx.x * 256 + threadIdx.x;  // n4 = 2048*2048/4
  ushort4 x = a[i], y = b[i];
  ushort4 r;
  r.x = f2bf(bf2f(x.x) + bf2f(y.x));
  r.y = f2bf(bf2f(x.y) + bf2f(y.y));
  r.z = f2bf(bf2f(x.z) + bf2f(y.z));
  r.w = f2bf(bf2f(x.w) + bf2f(y.w));
  o[i] = r;
}

// ---- 5) head: pre = 0.1*(cnt @ W_out) + b_out ; out = (pre/2 - 1 >= 0) ----
__global__ __launch_bounds__(256) void k_head(const unsigned short* __restrict__ cntb,
                                              const float* __restrict__ Wout,
                                              const float* __restrict__ bout,
                                              float* __restrict__ out) {
  __shared__ float Wl[HDIM * ADIM];  // 40 KB
  const int t = threadIdx.x;
  for (int i = t; i < HDIM * ADIM; i += 256) Wl[i] = Wout[i];
  __syncthreads();
  const int w = t >> 6, l = t & 63;
  #pragma unroll
  for (int rr = 0; rr < 4; ++rr) {
    const int row = blockIdx.x * 16 + w * 4 + rr;
    const unsigned short* rp = cntb + (size_t)row * HDIM;
    float acc[ADIM] = {};
    #pragma unroll
    for (int it = 0; it < 4; ++it) {
      const int k0 = it * 512 + l * 8;
      short8 v = *(const short8*)(rp + k0);
      #pragma unroll
      for (int jj = 0; jj < 8; ++jj) {
        const float c = bf2f((unsigned short)v[jj]);
        const int k = k0 + jj;
        #pragma unroll
        for (int a = 0; a < ADIM; ++a) acc[a] += c * Wl[k * ADIM + a];
      }
    }
    #pragma unroll
    for (int a = 0; a < ADIM; ++a)
      #pragma unroll
      for (int off = 32; off >= 1; off >>= 1)
        acc[a] += __shfl_down(acc[a], off, 64);
    if (l == 0) {
      #pragma unroll
      for (int a = 0; a < ADIM; ++a) {
        const float pre = acc[a] * 0.1f + bout[a];
        const float vout = pre * 0.5f;  // single-step LIF from v=0: v = pre/tau
        out[(size_t)row * ADIM + a] = (vout - 1.0f >= 0.0f) ? 1.0f : 0.0f;
      }
    }
  }
}

extern "C" void kernel_launch(void* const* d_in, const int* in_sizes, int n_in,
                              void* d_out, int out_size, void* d_ws, size_t ws_size,
                              hipStream_t stream) {
  const float* x     = (const float*)d_in[0];
  const float* W_in  = (const float*)d_in[1];
  const float* b_in  = (const float*)d_in[2];
  const float* W_snn = (const float*)d_in[3];
  const float* b_snn = (const float*)d_in[4];
  const float* W_out = (const float*)d_in[5];
  const float* b_out = (const float*)d_in[6];
  float* out = (float*)d_out;

  // workspace (48 MiB, proven available in R1):
  // [0,16M)   xb   : bf16 x [4096][2048]
  // [16,24M)  Winb : bf16 W_in [2048][2048]       (dead after GEMM-C)
  // [24,32M)  WsnT : bf16 W_snn^T [2048][2048]    (dead after GEMM-C)
  // [32,40M)  Cp0  : bf16 partial (K-half 0) -> WcT in-place after k_wcred
  // [40,48M)  Cp1  : bf16 partial (K-half 1)
  // [16,32M)  cnt  : bf16 spike counts [4096][2048] (reuses Winb/WsnT)
  // bc (fp32[2048]) lives in d_out scratch; k_head overwrites d_out at the end.
  char* ws = (char*)d_ws;
  unsigned short* xb   = (unsigned short*)(ws);
  unsigned short* Winb = (unsigned short*)(ws + (size_t)16 * 1024 * 1024);
  unsigned short* WsnT = (unsigned short*)(ws + (size_t)24 * 1024 * 1024);
  unsigned short* Cp0  = (unsigned short*)(ws + (size_t)32 * 1024 * 1024);
  unsigned short* Cp1  = (unsigned short*)(ws + (size_t)40 * 1024 * 1024);
  unsigned short* WcT  = Cp0;
  unsigned short* cntb = Winb;
  float* bc = (float*)d_out;  // 8 KB scratch; consumed by gemm<1>, then head overwrites

  // 1) prep: cvt x, cvt W_in, transpose W_snn, zero bc
  k_prep<<<13313, 256, 0, stream>>>(x, W_in, W_snn, xb, Winb, WsnT, bc);

  // 2) bc = b_in @ W_snn
  k_bc<<<64, 256, 0, stream>>>(b_in, W_snn, bc);

  // 3) Wc^T partials: Cp[kh][i][j] = sum_{k in half} W_snn[k][i] * W_in[j][k]
  k_gemm<0><<<512, 512, 0, stream>>>(WsnT, Winb, nullptr, nullptr, Cp0);

  // 4) WcT = Cp0 + Cp1 (in-place over Cp0)
  k_wcred<<<4096, 256, 0, stream>>>((const ushort4*)Cp0, (const ushort4*)Cp1,
                                    (ushort4*)WcT);

  // 5) cnt = LIF10(x @ Wc + bc + b_snn)
  k_gemm<1><<<512, 512, 0, stream>>>(xb, WcT, bc, b_snn, cntb);

  // 6) head
  k_head<<<BATCH / 16, 256, 0, stream>>>(cntb, W_out, b_out, out);
}